// Round 1
// baseline (210.358 us; speedup 1.0000x reference)
//
#include <hip/hip_runtime.h>

typedef __attribute__((ext_vector_type(8))) short bf16x8;
typedef __attribute__((ext_vector_type(4))) float f32x4;

#define MFMA_BF16 __builtin_amdgcn_mfma_f32_16x16x32_bf16

__device__ __forceinline__ unsigned short f2b(float f) {
  union { float f; unsigned u; } v; v.f = f;
  unsigned r = (v.u + 0x7FFFu + ((v.u >> 16) & 1u)) >> 16;
  return (unsigned short)r;
}

__device__ __forceinline__ void gload_lds16(const void* g, void* l) {
  __builtin_amdgcn_global_load_lds(
      (const __attribute__((address_space(1))) void*)g,
      (__attribute__((address_space(3))) void*)l, 16, 0, 0);
}

// ---------------- fp32 -> bf16 conversion (vectorized) ----------------
__global__ __launch_bounds__(256) void cvt_f32_bf16(const float* __restrict__ src,
                                                    unsigned short* __restrict__ dst,
                                                    int n4) {
  int i = blockIdx.x * 256 + threadIdx.x;
  if (i >= n4) return;
  float4 v = reinterpret_cast<const float4*>(src)[i];
  ushort4 o;
  o.x = f2b(v.x); o.y = f2b(v.y); o.z = f2b(v.z); o.w = f2b(v.w);
  reinterpret_cast<ushort4*>(dst)[i] = o;
}

// ---------------- fused QKV projection GEMM ----------------
// C = X[4096x1024] * W^T, W row-major [1024x1024] (torch Linear). 128x128 tile,
// BK=64, 4 waves each own a 64x64 quadrant. LDS tiles XOR-swizzled
// (byte ^= (row&7)<<4) via pre-swizzled global source for global_load_lds.
__global__ __launch_bounds__(256) void qkv_gemm(
    const unsigned short* __restrict__ X,
    const unsigned short* __restrict__ Wq, const unsigned short* __restrict__ Wk,
    const unsigned short* __restrict__ Wv,
    const float* __restrict__ bq, const float* __restrict__ bk,
    const float* __restrict__ bv,
    unsigned short* __restrict__ Qo, unsigned short* __restrict__ Ko,
    unsigned short* __restrict__ Vto) {
  __shared__ char smA[16384];
  __shared__ char smB[16384];
  const int tid = threadIdx.x, lane = tid & 63, wvid = tid >> 6;
  const int wr = wvid >> 1, wc = wvid & 1;
  const int m0 = blockIdx.x * 128;
  const int bnall = blockIdx.y;
  const int wsel = bnall >> 3;          // 0=Q 1=K 2=V
  const int n0 = (bnall & 7) * 128;
  const unsigned short* W = (wsel == 0) ? Wq : (wsel == 1) ? Wk : Wv;
  const float* bias = (wsel == 0) ? bq : (wsel == 1) ? bk : bv;

  f32x4 acc[4][4];
#pragma unroll
  for (int i = 0; i < 4; ++i)
#pragma unroll
    for (int j = 0; j < 4; ++j) acc[i][j] = (f32x4){0.f, 0.f, 0.f, 0.f};

  for (int kt = 0; kt < 16; ++kt) {
    const int k0 = kt * 64;
    __syncthreads();
#pragma unroll
    for (int i = 0; i < 4; ++i) {
      int c = (i * 4 + wvid) * 64 + lane;
      int row = c >> 3;
      int cb = (c & 7) ^ (row & 7);  // pre-swizzled source column block
      gload_lds16(X + (size_t)(m0 + row) * 1024 + k0 + cb * 8,
                  smA + (i * 4 + wvid) * 1024);
      gload_lds16(W + (size_t)(n0 + row) * 1024 + k0 + cb * 8,
                  smB + (i * 4 + wvid) * 1024);
    }
    __syncthreads();
    bf16x8 af[4][2], bfr[4][2];
#pragma unroll
    for (int mi = 0; mi < 4; ++mi)
#pragma unroll
      for (int ks = 0; ks < 2; ++ks) {
        int rowa = wr * 64 + mi * 16 + (lane & 15);
        int addra = (rowa * 128 + ks * 64 + ((lane >> 4) * 16)) ^ ((rowa & 7) << 4);
        af[mi][ks] = *(const bf16x8*)(smA + addra);
        int rowb = wc * 64 + mi * 16 + (lane & 15);
        int addrb = (rowb * 128 + ks * 64 + ((lane >> 4) * 16)) ^ ((rowb & 7) << 4);
        bfr[mi][ks] = *(const bf16x8*)(smB + addrb);
      }
#pragma unroll
    for (int ks = 0; ks < 2; ++ks)
#pragma unroll
      for (int mi = 0; mi < 4; ++mi)
#pragma unroll
        for (int ni = 0; ni < 4; ++ni)
          acc[mi][ni] = MFMA_BF16(af[mi][ks], bfr[ni][ks], acc[mi][ni], 0, 0, 0);
  }

  const float qscale = (wsel == 0) ? 0.125f : 1.0f;  // 1/sqrt(64)
#pragma unroll
  for (int mi = 0; mi < 4; ++mi)
#pragma unroll
    for (int ni = 0; ni < 4; ++ni)
#pragma unroll
      for (int r = 0; r < 4; ++r) {
        int m = m0 + wr * 64 + mi * 16 + (lane >> 4) * 4 + r;
        int n = n0 + wc * 64 + ni * 16 + (lane & 15);
        float v = (acc[mi][ni][r] + bias[n]) * qscale;
        int b = m >> 11, t = m & 2047;
        int h = n >> 6, hd = n & 63;
        unsigned short bv16 = f2b(v);
        if (wsel == 2)
          Vto[(((size_t)b * 16 + h) * 64 + hd) * 2048 + t] = bv16;   // V^T [B,H,64,T]
        else if (wsel == 1)
          Ko[(((size_t)b * 16 + h) * 2048 + t) * 64 + hd] = bv16;    // [B,H,T,64]
        else
          Qo[(((size_t)b * 16 + h) * 2048 + t) * 64 + hd] = bv16;
      }
}

// ---------------- flash attention ----------------
// grid (T/128, B*H). 4 waves/block, each wave owns 32 q-rows, Q in registers.
// K/V tiles (64 keys) staged via swizzled global_load_lds; online softmax in
// d-frag layout; P staged per-wave in swizzled LDS for the PV MFMA A-operand.
__global__ __launch_bounds__(256) void attn_kernel(
    const unsigned short* __restrict__ Qg, const unsigned short* __restrict__ Kg,
    const unsigned short* __restrict__ Vtg, unsigned short* __restrict__ Og) {
  __shared__ char smK[8192];
  __shared__ char smV[8192];
  __shared__ char smP[4][4096];
  const int tid = threadIdx.x, lane = tid & 63, wvid = tid >> 6;
  const int bh = blockIdx.y;
  const int q0 = blockIdx.x * 128 + wvid * 32;
  const unsigned short* Qh = Qg + (size_t)bh * 2048 * 64;
  const unsigned short* Kh = Kg + (size_t)bh * 2048 * 64;
  const unsigned short* Vh = Vtg + (size_t)bh * 64 * 2048;

  bf16x8 qf[2][2];
#pragma unroll
  for (int mi = 0; mi < 2; ++mi)
#pragma unroll
    for (int ks = 0; ks < 2; ++ks) {
      int row = q0 + mi * 16 + (lane & 15);
      int col = ks * 32 + ((lane >> 4) * 8);
      qf[mi][ks] = *(const bf16x8*)(Qh + (size_t)row * 64 + col);
    }

  f32x4 acc[2][4];
  float mrow[2][4], lrow[2][4];
#pragma unroll
  for (int mi = 0; mi < 2; ++mi) {
#pragma unroll
    for (int ni = 0; ni < 4; ++ni) acc[mi][ni] = (f32x4){0.f, 0.f, 0.f, 0.f};
#pragma unroll
    for (int r = 0; r < 4; ++r) { mrow[mi][r] = -1e30f; lrow[mi][r] = 0.f; }
  }

  for (int kt = 0; kt < 32; ++kt) {
    __syncthreads();
#pragma unroll
    for (int i = 0; i < 2; ++i) {
      int c = (i * 4 + wvid) * 64 + lane;
      int row = c >> 3;
      int cb = (c & 7) ^ (row & 7);
      gload_lds16(Kh + (size_t)(kt * 64 + row) * 64 + cb * 8,
                  smK + (i * 4 + wvid) * 1024);
      gload_lds16(Vh + (size_t)row * 2048 + kt * 64 + cb * 8,
                  smV + (i * 4 + wvid) * 1024);
    }
    __syncthreads();

    // S = Q K^T  (32x64 per wave)
    f32x4 s[2][4];
#pragma unroll
    for (int mi = 0; mi < 2; ++mi)
#pragma unroll
      for (int ni = 0; ni < 4; ++ni) s[mi][ni] = (f32x4){0.f, 0.f, 0.f, 0.f};
#pragma unroll
    for (int ks = 0; ks < 2; ++ks)
#pragma unroll
      for (int ni = 0; ni < 4; ++ni) {
        int row = ni * 16 + (lane & 15);
        int addr = (row * 128 + ks * 64 + ((lane >> 4) * 16)) ^ ((row & 7) << 4);
        bf16x8 kb = *(const bf16x8*)(smK + addr);
#pragma unroll
        for (int mi = 0; mi < 2; ++mi)
          s[mi][ni] = MFMA_BF16(qf[mi][ks], kb, s[mi][ni], 0, 0, 0);
      }

    // online softmax (row = (lane>>4)*4+r; 16 lanes l&15 share a row)
#pragma unroll
    for (int mi = 0; mi < 2; ++mi)
#pragma unroll
      for (int r = 0; r < 4; ++r) {
        float mx = fmaxf(fmaxf(s[mi][0][r], s[mi][1][r]),
                         fmaxf(s[mi][2][r], s[mi][3][r]));
#pragma unroll
        for (int d = 1; d < 16; d <<= 1) mx = fmaxf(mx, __shfl_xor(mx, d, 64));
        float mnew = fmaxf(mrow[mi][r], mx);
        float alpha = __expf(mrow[mi][r] - mnew);
        float ps = 0.f;
#pragma unroll
        for (int ni = 0; ni < 4; ++ni) {
          float p = __expf(s[mi][ni][r] - mnew);
          s[mi][ni][r] = p;
          ps += p;
        }
#pragma unroll
        for (int d = 1; d < 16; d <<= 1) ps += __shfl_xor(ps, d, 64);
        lrow[mi][r] = lrow[mi][r] * alpha + ps;
        mrow[mi][r] = mnew;
#pragma unroll
        for (int ni = 0; ni < 4; ++ni) acc[mi][ni][r] *= alpha;
      }

    // P -> LDS (bf16, swizzled rows)
    char* myP = smP[wvid];
#pragma unroll
    for (int mi = 0; mi < 2; ++mi)
#pragma unroll
      for (int ni = 0; ni < 4; ++ni)
#pragma unroll
        for (int r = 0; r < 4; ++r) {
          int row = mi * 16 + (lane >> 4) * 4 + r;
          int col = ni * 16 + (lane & 15);
          int addr = (row * 128 + col * 2) ^ ((row & 7) << 4);
          *(unsigned short*)(myP + addr) = f2b(s[mi][ni][r]);
        }

    // O += P V
#pragma unroll
    for (int ks = 0; ks < 2; ++ks) {
      bf16x8 pa[2];
#pragma unroll
      for (int mi = 0; mi < 2; ++mi) {
        int prow = mi * 16 + (lane & 15);
        int paddr = (prow * 128 + ks * 64 + ((lane >> 4) * 16)) ^ ((prow & 7) << 4);
        pa[mi] = *(const bf16x8*)(myP + paddr);
      }
#pragma unroll
      for (int ni = 0; ni < 4; ++ni) {
        int vrow = ni * 16 + (lane & 15);
        int vaddr = (vrow * 128 + ks * 64 + ((lane >> 4) * 16)) ^ ((vrow & 7) << 4);
        bf16x8 vb = *(const bf16x8*)(smV + vaddr);
#pragma unroll
        for (int mi = 0; mi < 2; ++mi)
          acc[mi][ni] = MFMA_BF16(pa[mi], vb, acc[mi][ni], 0, 0, 0);
      }
    }
  }

  // epilogue: normalize, write O as [B,T,D] bf16
  const int b = bh >> 4, h = bh & 15;
#pragma unroll
  for (int mi = 0; mi < 2; ++mi)
#pragma unroll
    for (int r = 0; r < 4; ++r) {
      float inv = 1.0f / lrow[mi][r];
      int t = q0 + mi * 16 + (lane >> 4) * 4 + r;
#pragma unroll
      for (int ni = 0; ni < 4; ++ni) {
        int d = ni * 16 + (lane & 15);
        Og[((size_t)(b * 2048 + t)) * 1024 + h * 64 + d] = f2b(acc[mi][ni][r] * inv);
      }
    }
}

// ---------------- output projection GEMM (fp32 out + bias) ----------------
__global__ __launch_bounds__(256) void out_gemm(
    const unsigned short* __restrict__ A, const unsigned short* __restrict__ W,
    const float* __restrict__ bias, float* __restrict__ out) {
  __shared__ char smA[16384];
  __shared__ char smB[16384];
  const int tid = threadIdx.x, lane = tid & 63, wvid = tid >> 6;
  const int wr = wvid >> 1, wc = wvid & 1;
  const int m0 = blockIdx.x * 128;
  const int n0 = blockIdx.y * 128;

  f32x4 acc[4][4];
#pragma unroll
  for (int i = 0; i < 4; ++i)
#pragma unroll
    for (int j = 0; j < 4; ++j) acc[i][j] = (f32x4){0.f, 0.f, 0.f, 0.f};

  for (int kt = 0; kt < 16; ++kt) {
    const int k0 = kt * 64;
    __syncthreads();
#pragma unroll
    for (int i = 0; i < 4; ++i) {
      int c = (i * 4 + wvid) * 64 + lane;
      int row = c >> 3;
      int cb = (c & 7) ^ (row & 7);
      gload_lds16(A + (size_t)(m0 + row) * 1024 + k0 + cb * 8,
                  smA + (i * 4 + wvid) * 1024);
      gload_lds16(W + (size_t)(n0 + row) * 1024 + k0 + cb * 8,
                  smB + (i * 4 + wvid) * 1024);
    }
    __syncthreads();
    bf16x8 af[4][2], bfr[4][2];
#pragma unroll
    for (int mi = 0; mi < 4; ++mi)
#pragma unroll
      for (int ks = 0; ks < 2; ++ks) {
        int rowa = wr * 64 + mi * 16 + (lane & 15);
        int addra = (rowa * 128 + ks * 64 + ((lane >> 4) * 16)) ^ ((rowa & 7) << 4);
        af[mi][ks] = *(const bf16x8*)(smA + addra);
        int rowb = wc * 64 + mi * 16 + (lane & 15);
        int addrb = (rowb * 128 + ks * 64 + ((lane >> 4) * 16)) ^ ((rowb & 7) << 4);
        bfr[mi][ks] = *(const bf16x8*)(smB + addrb);
      }
#pragma unroll
    for (int ks = 0; ks < 2; ++ks)
#pragma unroll
      for (int mi = 0; mi < 4; ++mi)
#pragma unroll
        for (int ni = 0; ni < 4; ++ni)
          acc[mi][ni] = MFMA_BF16(af[mi][ks], bfr[ni][ks], acc[mi][ni], 0, 0, 0);
  }

#pragma unroll
  for (int mi = 0; mi < 4; ++mi)
#pragma unroll
    for (int ni = 0; ni < 4; ++ni)
#pragma unroll
      for (int r = 0; r < 4; ++r) {
        int m = m0 + wr * 64 + mi * 16 + (lane >> 4) * 4 + r;
        int n = n0 + wc * 64 + ni * 16 + (lane & 15);
        out[(size_t)m * 1024 + n] = acc[mi][ni][r] + bias[n];
      }
}

extern "C" void kernel_launch(void* const* d_in, const int* in_sizes, int n_in,
                              void* d_out, int out_size, void* d_ws, size_t ws_size,
                              hipStream_t stream) {
  const float* x = (const float*)d_in[0];
  const float* Wq = (const float*)d_in[1];
  const float* bq = (const float*)d_in[2];
  const float* Wk = (const float*)d_in[3];
  const float* bk = (const float*)d_in[4];
  const float* Wv = (const float*)d_in[5];
  const float* bv = (const float*)d_in[6];
  const float* Wo = (const float*)d_in[7];
  const float* bo = (const float*)d_in[8];
  float* out = (float*)d_out;
  char* ws = (char*)d_ws;

  // layout (bytes): [0,8M) xb, then Ob reuses it after qkv_gemm is done
  unsigned short* xb = (unsigned short*)(ws + 0);
  unsigned short* Ob = (unsigned short*)(ws + 0);  // reuse: attn writes after qkv reads
  unsigned short* wqb = (unsigned short*)(ws + 8388608);
  unsigned short* wkb = (unsigned short*)(ws + 10485760);
  unsigned short* wvb = (unsigned short*)(ws + 12582912);
  unsigned short* wob = (unsigned short*)(ws + 14680064);
  unsigned short* Qb = (unsigned short*)(ws + 16777216);
  unsigned short* Kb = (unsigned short*)(ws + 25165824);
  unsigned short* Vtb = (unsigned short*)(ws + 33554432);

  hipLaunchKernelGGL(cvt_f32_bf16, dim3(4096), dim3(256), 0, stream, x, xb, 1048576);
  hipLaunchKernelGGL(cvt_f32_bf16, dim3(1024), dim3(256), 0, stream, Wq, wqb, 262144);
  hipLaunchKernelGGL(cvt_f32_bf16, dim3(1024), dim3(256), 0, stream, Wk, wkb, 262144);
  hipLaunchKernelGGL(cvt_f32_bf16, dim3(1024), dim3(256), 0, stream, Wv, wvb, 262144);
  hipLaunchKernelGGL(cvt_f32_bf16, dim3(1024), dim3(256), 0, stream, Wo, wob, 262144);
  hipLaunchKernelGGL(qkv_gemm, dim3(32, 24), dim3(256), 0, stream, xb, wqb, wkb, wvb,
                     bq, bk, bv, Qb, Kb, Vtb);
  hipLaunchKernelGGL(attn_kernel, dim3(16, 32), dim3(256), 0, stream, Qb, Kb, Vtb, Ob);
  hipLaunchKernelGGL(out_gemm, dim3(32, 8), dim3(256), 0, stream, Ob, wob, bo, out);
}

// Round 3
// 163.898 us; speedup vs baseline: 1.2835x; 1.2835x over previous
//
#include <hip/hip_runtime.h>
#include <cmath>

typedef __attribute__((ext_vector_type(8))) short bf16x8;
typedef __attribute__((ext_vector_type(4))) float f32x4;

#define MFMA_BF16 __builtin_amdgcn_mfma_f32_16x16x32_bf16

__device__ __forceinline__ unsigned short f2b(float f) {
  union { float f; unsigned u; } v; v.f = f;
  unsigned r = (v.u + 0x7FFFu + ((v.u >> 16) & 1u)) >> 16;
  return (unsigned short)r;
}

__device__ __forceinline__ unsigned cvt_pk_bf16(float lo, float hi) {
  unsigned r;
  asm("v_cvt_pk_bf16_f32 %0, %1, %2" : "=v"(r) : "v"(lo), "v"(hi));
  return r;
}

__device__ __forceinline__ float fast_exp2(float x) {
  float r;
  asm("v_exp_f32 %0, %1" : "=v"(r) : "v"(x));
  return r;
}

__device__ __forceinline__ void gload_lds16(const void* g, void* l) {
  __builtin_amdgcn_global_load_lds(
      (const __attribute__((address_space(1))) void*)g,
      (__attribute__((address_space(3))) void*)l, 16, 0, 0);
}

// ---------------- fp32 -> bf16 conversion (vectorized) ----------------
__global__ __launch_bounds__(256) void cvt_f32_bf16(const float* __restrict__ src,
                                                    unsigned short* __restrict__ dst,
                                                    int n4) {
  int i = blockIdx.x * 256 + threadIdx.x;
  if (i >= n4) return;
  float4 v = reinterpret_cast<const float4*>(src)[i];
  ushort4 o;
  o.x = f2b(v.x); o.y = f2b(v.y); o.z = f2b(v.z); o.w = f2b(v.w);
  reinterpret_cast<ushort4*>(dst)[i] = o;
}

// all four weight matrices in one launch (blockIdx.y selects)
__global__ __launch_bounds__(256) void cvt4_f32_bf16(
    const float* __restrict__ s0, const float* __restrict__ s1,
    const float* __restrict__ s2, const float* __restrict__ s3,
    unsigned short* __restrict__ d0, unsigned short* __restrict__ d1,
    unsigned short* __restrict__ d2, unsigned short* __restrict__ d3) {
  const float* src = (blockIdx.y == 0) ? s0 : (blockIdx.y == 1) ? s1
                   : (blockIdx.y == 2) ? s2 : s3;
  unsigned short* dst = (blockIdx.y == 0) ? d0 : (blockIdx.y == 1) ? d1
                      : (blockIdx.y == 2) ? d2 : d3;
  int i = blockIdx.x * 256 + threadIdx.x;
  float4 v = reinterpret_cast<const float4*>(src)[i];
  ushort4 o;
  o.x = f2b(v.x); o.y = f2b(v.y); o.z = f2b(v.z); o.w = f2b(v.w);
  reinterpret_cast<ushort4*>(dst)[i] = o;
}

// ---------------- fused QKV projection GEMM ----------------
// C = X[4096x1024] * W^T, W row-major [1024x1024] (torch Linear). 128x128 tile,
// BK=64, 4 waves each own a 64x64 quadrant. LDS tiles XOR-swizzled
// (byte ^= (row&7)<<4) via pre-swizzled global source for global_load_lds.
__global__ __launch_bounds__(256) void qkv_gemm(
    const unsigned short* __restrict__ X,
    const unsigned short* __restrict__ Wq, const unsigned short* __restrict__ Wk,
    const unsigned short* __restrict__ Wv,
    const float* __restrict__ bq, const float* __restrict__ bk,
    const float* __restrict__ bv,
    unsigned short* __restrict__ Qo, unsigned short* __restrict__ Ko,
    unsigned short* __restrict__ Vto) {
  __shared__ char smA[16384];
  __shared__ char smB[16384];
  const int tid = threadIdx.x, lane = tid & 63, wvid = tid >> 6;
  const int wr = wvid >> 1, wc = wvid & 1;
  const int m0 = blockIdx.x * 128;
  const int bnall = blockIdx.y;
  const int wsel = bnall >> 3;          // 0=Q 1=K 2=V
  const int n0 = (bnall & 7) * 128;
  const unsigned short* W = (wsel == 0) ? Wq : (wsel == 1) ? Wk : Wv;
  const float* bias = (wsel == 0) ? bq : (wsel == 1) ? bk : bv;

  f32x4 acc[4][4];
#pragma unroll
  for (int i = 0; i < 4; ++i)
#pragma unroll
    for (int j = 0; j < 4; ++j) acc[i][j] = (f32x4){0.f, 0.f, 0.f, 0.f};

  for (int kt = 0; kt < 16; ++kt) {
    const int k0 = kt * 64;
    __syncthreads();
#pragma unroll
    for (int i = 0; i < 4; ++i) {
      int c = (i * 4 + wvid) * 64 + lane;
      int row = c >> 3;
      int cb = (c & 7) ^ (row & 7);  // pre-swizzled source column block
      gload_lds16(X + (size_t)(m0 + row) * 1024 + k0 + cb * 8,
                  smA + (i * 4 + wvid) * 1024);
      gload_lds16(W + (size_t)(n0 + row) * 1024 + k0 + cb * 8,
                  smB + (i * 4 + wvid) * 1024);
    }
    __syncthreads();
    bf16x8 af[4][2], bfr[4][2];
#pragma unroll
    for (int mi = 0; mi < 4; ++mi)
#pragma unroll
      for (int ks = 0; ks < 2; ++ks) {
        int rowa = wr * 64 + mi * 16 + (lane & 15);
        int addra = (rowa * 128 + ks * 64 + ((lane >> 4) * 16)) ^ ((rowa & 7) << 4);
        af[mi][ks] = *(const bf16x8*)(smA + addra);
        int rowb = wc * 64 + mi * 16 + (lane & 15);
        int addrb = (rowb * 128 + ks * 64 + ((lane >> 4) * 16)) ^ ((rowb & 7) << 4);
        bfr[mi][ks] = *(const bf16x8*)(smB + addrb);
      }
#pragma unroll
    for (int ks = 0; ks < 2; ++ks)
#pragma unroll
      for (int mi = 0; mi < 4; ++mi)
#pragma unroll
        for (int ni = 0; ni < 4; ++ni)
          acc[mi][ni] = MFMA_BF16(af[mi][ks], bfr[ni][ks], acc[mi][ni], 0, 0, 0);
  }

  // Q scale folds 1/sqrt(64) AND log2(e) so attention can use exp2 directly.
  const float qscale = (wsel == 0) ? 0.125f * 1.44269504f : 1.0f;
#pragma unroll
  for (int mi = 0; mi < 4; ++mi)
#pragma unroll
    for (int ni = 0; ni < 4; ++ni)
#pragma unroll
      for (int r = 0; r < 4; ++r) {
        int m = m0 + wr * 64 + mi * 16 + (lane >> 4) * 4 + r;
        int n = n0 + wc * 64 + ni * 16 + (lane & 15);
        float v = (acc[mi][ni][r] + bias[n]) * qscale;
        int b = m >> 11, t = m & 2047;
        int h = n >> 6, hd = n & 63;
        unsigned short bv16 = f2b(v);
        if (wsel == 2)
          Vto[(((size_t)b * 16 + h) * 64 + hd) * 2048 + t] = bv16;   // V^T [B,H,64,T]
        else if (wsel == 1)
          Ko[(((size_t)b * 16 + h) * 2048 + t) * 64 + hd] = bv16;    // [B,H,T,64]
        else
          Qo[(((size_t)b * 16 + h) * 2048 + t) * 64 + hd] = bv16;
      }
}

// ---------------- flash attention (swapped-operand, dbuf staging) ----------------
// grid (T/128, B*H), 4 waves/block, 32 q-rows/wave, Q in registers.
// S^T = mfma(K,Q) so each lane owns its q-row stats (2 shuffles per reduce);
// P^T packed via v_cvt_pk_bf16_f32 -> ds_write_b64 into swizzled LDS;
// O^T = mfma(V^T, P^T) so the alpha-rescale is lane-local.
__global__ __launch_bounds__(256) void attn_kernel(
    const unsigned short* __restrict__ Qg, const unsigned short* __restrict__ Kg,
    const unsigned short* __restrict__ Vtg, unsigned short* __restrict__ Og) {
  __shared__ char smK[2][8192];
  __shared__ char smV[2][8192];
  __shared__ char smPT[4][4096];
  const int tid = threadIdx.x, lane = tid & 63, wvid = tid >> 6;
  const int g = lane >> 4, l15 = lane & 15;
  const int bh = blockIdx.y;
  const int q0 = blockIdx.x * 128 + wvid * 32;
  const unsigned short* Qh = Qg + (size_t)bh * 2048 * 64;
  const unsigned short* Kh = Kg + (size_t)bh * 2048 * 64;
  const unsigned short* Vh = Vtg + (size_t)bh * 64 * 2048;

  // Q fragments (used as MFMA B operand: col q = l15, rows d = g*8+j)
  bf16x8 qf[2][2];
#pragma unroll
  for (int qi = 0; qi < 2; ++qi)
#pragma unroll
    for (int ks = 0; ks < 2; ++ks) {
      int row = q0 + qi * 16 + l15;
      int col = ks * 32 + g * 8;
      qf[qi][ks] = *(const bf16x8*)(Qh + (size_t)row * 64 + col);
    }

  f32x4 acc[4][2];   // O^T frags: [di][qi], row d = di*16+4g+r, col q = qi*16+l15
#pragma unroll
  for (int di = 0; di < 4; ++di)
#pragma unroll
    for (int qi = 0; qi < 2; ++qi) acc[di][qi] = (f32x4){0.f, 0.f, 0.f, 0.f};
  float m[2] = {-1e30f, -1e30f}, l[2] = {0.f, 0.f};

#define STAGE(buf, kt)                                                         \
  {                                                                            \
    _Pragma("unroll") for (int i = 0; i < 2; ++i) {                            \
      int c = (i * 4 + wvid) * 64 + lane;                                      \
      int row = c >> 3;                                                        \
      int cb = (c & 7) ^ (row & 7);                                            \
      gload_lds16(Kh + (size_t)((kt) * 64 + row) * 64 + cb * 8,                \
                  smK[buf] + (i * 4 + wvid) * 1024);                           \
      gload_lds16(Vh + (size_t)row * 2048 + (kt) * 64 + cb * 8,                \
                  smV[buf] + (i * 4 + wvid) * 1024);                           \
    }                                                                          \
  }

  STAGE(0, 0);
  __syncthreads();
  int buf = 0;
  char* P = smPT[wvid];

  for (int kt = 0; kt < 32; ++kt) {
    if (kt < 31) STAGE(buf ^ 1, kt + 1);   // issue next-tile loads early (T3-lite)

    // S^T = K * Q^T  (64k x 32q per wave)
    f32x4 st[4][2];
#pragma unroll
    for (int ki = 0; ki < 4; ++ki)
#pragma unroll
      for (int qi = 0; qi < 2; ++qi) st[ki][qi] = (f32x4){0.f, 0.f, 0.f, 0.f};
#pragma unroll
    for (int ks = 0; ks < 2; ++ks)
#pragma unroll
      for (int ki = 0; ki < 4; ++ki) {
        int row = ki * 16 + l15;
        int addr = (row * 128 + ks * 64 + g * 16) ^ ((row & 7) << 4);
        bf16x8 kb = *(const bf16x8*)(smK[buf] + addr);
#pragma unroll
        for (int qi = 0; qi < 2; ++qi)
          st[ki][qi] = MFMA_BF16(kb, qf[qi][ks], st[ki][qi], 0, 0, 0);
      }

    // online softmax: lane owns q = qi*16+l15; k-coverage needs xor16+xor32 only
#pragma unroll
    for (int qi = 0; qi < 2; ++qi) {
      float mx = -1e30f;
#pragma unroll
      for (int ki = 0; ki < 4; ++ki)
#pragma unroll
        for (int r = 0; r < 4; ++r) mx = fmaxf(mx, st[ki][qi][r]);
      mx = fmaxf(mx, __shfl_xor(mx, 16, 64));
      mx = fmaxf(mx, __shfl_xor(mx, 32, 64));
      float mnew = fmaxf(m[qi], mx);
      float alpha = fast_exp2(m[qi] - mnew);
      float ps = 0.f;
#pragma unroll
      for (int ki = 0; ki < 4; ++ki)
#pragma unroll
        for (int r = 0; r < 4; ++r) {
          float p = fast_exp2(st[ki][qi][r] - mnew);
          st[ki][qi][r] = p;
          ps += p;
        }
      ps += __shfl_xor(ps, 16, 64);
      ps += __shfl_xor(ps, 32, 64);
      l[qi] = l[qi] * alpha + ps;
      m[qi] = mnew;
#pragma unroll
      for (int di = 0; di < 4; ++di) acc[di][qi] *= alpha;
    }

    // P^T -> LDS: r-pairs are k-consecutive -> cvt_pk + b64 writes
#pragma unroll
    for (int qi = 0; qi < 2; ++qi)
#pragma unroll
      for (int ki = 0; ki < 4; ++ki) {
        uint2 w;
        w.x = cvt_pk_bf16(st[ki][qi][0], st[ki][qi][1]);
        w.y = cvt_pk_bf16(st[ki][qi][2], st[ki][qi][3]);
        int q = qi * 16 + l15;
        int addr = (q * 128 + ki * 32 + g * 8) ^ ((q & 7) << 4);
        *(uint2*)(P + addr) = w;
      }

    // O^T += V^T * P^T
#pragma unroll
    for (int ks = 0; ks < 2; ++ks) {
      bf16x8 pb[2];
#pragma unroll
      for (int qi = 0; qi < 2; ++qi) {
        int q = qi * 16 + l15;
        int addr = (q * 128 + ks * 64 + g * 16) ^ ((q & 7) << 4);
        pb[qi] = *(const bf16x8*)(P + addr);
      }
#pragma unroll
      for (int di = 0; di < 4; ++di) {
        int d = di * 16 + l15;
        int vaddr = (d * 128 + ks * 64 + g * 16) ^ ((d & 7) << 4);
        bf16x8 vb = *(const bf16x8*)(smV[buf] + vaddr);
#pragma unroll
        for (int qi = 0; qi < 2; ++qi)
          acc[di][qi] = MFMA_BF16(vb, pb[qi], acc[di][qi], 0, 0, 0);
      }
    }

    __syncthreads();
    buf ^= 1;
  }

  // epilogue: normalize, transpose O^T -> O through LDS, coalesced 16B stores
  float inv[2] = {1.f / l[0], 1.f / l[1]};
#pragma unroll
  for (int qi = 0; qi < 2; ++qi)
#pragma unroll
    for (int di = 0; di < 4; ++di) {
      uint2 w;
      w.x = cvt_pk_bf16(acc[di][qi][0] * inv[qi], acc[di][qi][1] * inv[qi]);
      w.y = cvt_pk_bf16(acc[di][qi][2] * inv[qi], acc[di][qi][3] * inv[qi]);
      int q = qi * 16 + l15;
      int addr = (q * 128 + di * 32 + g * 8) ^ ((q & 7) << 4);
      *(uint2*)(P + addr) = w;
    }
  const int b = bh >> 4, h = bh & 15;
#pragma unroll
  for (int i = 0; i < 4; ++i) {
    int c = i * 64 + lane;
    int q = c >> 3, cb = c & 7;
    int addr = (q * 128 + cb * 16) ^ ((q & 7) << 4);
    uint4 v = *(const uint4*)(P + addr);
    int t = q0 + q;
    *(uint4*)(Og + ((size_t)(b * 2048 + t)) * 1024 + h * 64 + cb * 8) = v;
  }
}

// ---------------- output projection GEMM (fp32 out + bias) ----------------
__global__ __launch_bounds__(256) void out_gemm(
    const unsigned short* __restrict__ A, const unsigned short* __restrict__ W,
    const float* __restrict__ bias, float* __restrict__ out) {
  __shared__ char smA[16384];
  __shared__ char smB[16384];
  const int tid = threadIdx.x, lane = tid & 63, wvid = tid >> 6;
  const int wr = wvid >> 1, wc = wvid & 1;
  const int m0 = blockIdx.x * 128;
  const int n0 = blockIdx.y * 128;

  f32x4 acc[4][4];
#pragma unroll
  for (int i = 0; i < 4; ++i)
#pragma unroll
    for (int j = 0; j < 4; ++j) acc[i][j] = (f32x4){0.f, 0.f, 0.f, 0.f};

  for (int kt = 0; kt < 16; ++kt) {
    const int k0 = kt * 64;
    __syncthreads();
#pragma unroll
    for (int i = 0; i < 4; ++i) {
      int c = (i * 4 + wvid) * 64 + lane;
      int row = c >> 3;
      int cb = (c & 7) ^ (row & 7);
      gload_lds16(A + (size_t)(m0 + row) * 1024 + k0 + cb * 8,
                  smA + (i * 4 + wvid) * 1024);
      gload_lds16(W + (size_t)(n0 + row) * 1024 + k0 + cb * 8,
                  smB + (i * 4 + wvid) * 1024);
    }
    __syncthreads();
    bf16x8 af[4][2], bfr[4][2];
#pragma unroll
    for (int mi = 0; mi < 4; ++mi)
#pragma unroll
      for (int ks = 0; ks < 2; ++ks) {
        int rowa = wr * 64 + mi * 16 + (lane & 15);
        int addra = (rowa * 128 + ks * 64 + ((lane >> 4) * 16)) ^ ((rowa & 7) << 4);
        af[mi][ks] = *(const bf16x8*)(smA + addra);
        int rowb = wc * 64 + mi * 16 + (lane & 15);
        int addrb = (rowb * 128 + ks * 64 + ((lane >> 4) * 16)) ^ ((rowb & 7) << 4);
        bfr[mi][ks] = *(const bf16x8*)(smB + addrb);
      }
#pragma unroll
    for (int ks = 0; ks < 2; ++ks)
#pragma unroll
      for (int mi = 0; mi < 4; ++mi)
#pragma unroll
        for (int ni = 0; ni < 4; ++ni)
          acc[mi][ni] = MFMA_BF16(af[mi][ks], bfr[ni][ks], acc[mi][ni], 0, 0, 0);
  }

#pragma unroll
  for (int mi = 0; mi < 4; ++mi)
#pragma unroll
    for (int ni = 0; ni < 4; ++ni)
#pragma unroll
      for (int r = 0; r < 4; ++r) {
        int m = m0 + wr * 64 + mi * 16 + (lane >> 4) * 4 + r;
        int n = n0 + wc * 64 + ni * 16 + (lane & 15);
        out[(size_t)m * 1024 + n] = acc[mi][ni][r] + bias[n];
      }
}

extern "C" void kernel_launch(void* const* d_in, const int* in_sizes, int n_in,
                              void* d_out, int out_size, void* d_ws, size_t ws_size,
                              hipStream_t stream) {
  const float* x = (const float*)d_in[0];
  const float* Wq = (const float*)d_in[1];
  const float* bq = (const float*)d_in[2];
  const float* Wk = (const float*)d_in[3];
  const float* bk = (const float*)d_in[4];
  const float* Wv = (const float*)d_in[5];
  const float* bv = (const float*)d_in[6];
  const float* Wo = (const float*)d_in[7];
  const float* bo = (const float*)d_in[8];
  float* out = (float*)d_out;
  char* ws = (char*)d_ws;

  unsigned short* xb = (unsigned short*)(ws + 0);
  unsigned short* Ob = (unsigned short*)(ws + 0);  // reuse: attn writes after qkv reads
  unsigned short* wqb = (unsigned short*)(ws + 8388608);
  unsigned short* wkb = (unsigned short*)(ws + 10485760);
  unsigned short* wvb = (unsigned short*)(ws + 12582912);
  unsigned short* wob = (unsigned short*)(ws + 14680064);
  unsigned short* Qb = (unsigned short*)(ws + 16777216);
  unsigned short* Kb = (unsigned short*)(ws + 25165824);
  unsigned short* Vtb = (unsigned short*)(ws + 33554432);

  hipLaunchKernelGGL(cvt_f32_bf16, dim3(4096), dim3(256), 0, stream, x, xb, 1048576);
  hipLaunchKernelGGL(cvt4_f32_bf16, dim3(1024, 4), dim3(256), 0, stream,
                     Wq, Wk, Wv, Wo, wqb, wkb, wvb, wob);
  hipLaunchKernelGGL(qkv_gemm, dim3(32, 24), dim3(256), 0, stream, xb, wqb, wkb, wvb,
                     bq, bk, bv, Qb, Kb, Vtb);
  hipLaunchKernelGGL(attn_kernel, dim3(16, 32), dim3(256), 0, stream, Qb, Kb, Vtb, Ob);
  hipLaunchKernelGGL(out_gemm, dim3(32, 8), dim3(256), 0, stream, Ob, wob, bo, out);
}

// Round 4
// 149.229 us; speedup vs baseline: 1.4096x; 1.0983x over previous
//
#include <hip/hip_runtime.h>
#include <cmath>

typedef __attribute__((ext_vector_type(8))) short bf16x8;
typedef __attribute__((ext_vector_type(4))) float f32x4;

#define MFMA_BF16 __builtin_amdgcn_mfma_f32_16x16x32_bf16

__device__ __forceinline__ unsigned short f2b(float f) {
  union { float f; unsigned u; } v; v.f = f;
  unsigned r = (v.u + 0x7FFFu + ((v.u >> 16) & 1u)) >> 16;
  return (unsigned short)r;
}

__device__ __forceinline__ unsigned cvt_pk_bf16(float lo, float hi) {
  unsigned r;
  asm("v_cvt_pk_bf16_f32 %0, %1, %2" : "=v"(r) : "v"(lo), "v"(hi));
  return r;
}

__device__ __forceinline__ float fast_exp2(float x) {
  float r;
  asm("v_exp_f32 %0, %1" : "=v"(r) : "v"(x));
  return r;
}

__device__ __forceinline__ void gload_lds16(const void* g, void* l) {
  __builtin_amdgcn_global_load_lds(
      (const __attribute__((address_space(1))) void*)g,
      (__attribute__((address_space(3))) void*)l, 16, 0, 0);
}

// ---------------- all fp32->bf16 conversions in ONE launch ----------------
// regions (float4 units): x 1048576 | Wq 262144 | Wk | Wv | Wo
__global__ __launch_bounds__(256) void cvt_all(
    const float* __restrict__ x, const float* __restrict__ Wq,
    const float* __restrict__ Wk, const float* __restrict__ Wv,
    const float* __restrict__ Wo,
    unsigned short* __restrict__ xb, unsigned short* __restrict__ wqb,
    unsigned short* __restrict__ wkb, unsigned short* __restrict__ wvb,
    unsigned short* __restrict__ wob) {
  int i = blockIdx.x * 256 + threadIdx.x;
  const float* src; unsigned short* dst; int off;
  if (i < 1048576)      { src = x;  dst = xb;  off = i; }
  else if (i < 1310720) { src = Wq; dst = wqb; off = i - 1048576; }
  else if (i < 1572864) { src = Wk; dst = wkb; off = i - 1310720; }
  else if (i < 1835008) { src = Wv; dst = wvb; off = i - 1572864; }
  else                  { src = Wo; dst = wob; off = i - 1835008; }
  float4 v = reinterpret_cast<const float4*>(src)[off];
  ushort4 o;
  o.x = f2b(v.x); o.y = f2b(v.y); o.z = f2b(v.z); o.w = f2b(v.w);
  reinterpret_cast<ushort4*>(dst)[off] = o;
}

// ---------------- fused QKV projection GEMM ----------------
__global__ __launch_bounds__(256) void qkv_gemm(
    const unsigned short* __restrict__ X,
    const unsigned short* __restrict__ Wq, const unsigned short* __restrict__ Wk,
    const unsigned short* __restrict__ Wv,
    const float* __restrict__ bq, const float* __restrict__ bk,
    const float* __restrict__ bv,
    unsigned short* __restrict__ Qo, unsigned short* __restrict__ Ko,
    unsigned short* __restrict__ Vto) {
  __shared__ char smA[16384];
  __shared__ char smB[16384];
  const int tid = threadIdx.x, lane = tid & 63, wvid = tid >> 6;
  const int wr = wvid >> 1, wc = wvid & 1;
  // XCD-chunked swizzle (768 blocks, 96/XCD)
  const int lin = blockIdx.y * 32 + blockIdx.x;
  const int wg = (lin & 7) * 96 + (lin >> 3);
  const int m0 = (wg & 31) * 128;
  const int bnall = wg >> 5;
  const int wsel = bnall >> 3;          // 0=Q 1=K 2=V
  const int n0 = (bnall & 7) * 128;
  const unsigned short* W = (wsel == 0) ? Wq : (wsel == 1) ? Wk : Wv;
  const float* bias = (wsel == 0) ? bq : (wsel == 1) ? bk : bv;

  f32x4 acc[4][4];
#pragma unroll
  for (int i = 0; i < 4; ++i)
#pragma unroll
    for (int j = 0; j < 4; ++j) acc[i][j] = (f32x4){0.f, 0.f, 0.f, 0.f};

  for (int kt = 0; kt < 16; ++kt) {
    const int k0 = kt * 64;
    __syncthreads();
#pragma unroll
    for (int i = 0; i < 4; ++i) {
      int c = (i * 4 + wvid) * 64 + lane;
      int row = c >> 3;
      int cb = (c & 7) ^ (row & 7);  // pre-swizzled source column block
      gload_lds16(X + (size_t)(m0 + row) * 1024 + k0 + cb * 8,
                  smA + (i * 4 + wvid) * 1024);
      gload_lds16(W + (size_t)(n0 + row) * 1024 + k0 + cb * 8,
                  smB + (i * 4 + wvid) * 1024);
    }
    __syncthreads();
    bf16x8 af[4][2], bfr[4][2];
#pragma unroll
    for (int mi = 0; mi < 4; ++mi)
#pragma unroll
      for (int ks = 0; ks < 2; ++ks) {
        int rowa = wr * 64 + mi * 16 + (lane & 15);
        int addra = (rowa * 128 + ks * 64 + ((lane >> 4) * 16)) ^ ((rowa & 7) << 4);
        af[mi][ks] = *(const bf16x8*)(smA + addra);
        int rowb = wc * 64 + mi * 16 + (lane & 15);
        int addrb = (rowb * 128 + ks * 64 + ((lane >> 4) * 16)) ^ ((rowb & 7) << 4);
        bfr[mi][ks] = *(const bf16x8*)(smB + addrb);
      }
#pragma unroll
    for (int ks = 0; ks < 2; ++ks)
#pragma unroll
      for (int mi = 0; mi < 4; ++mi)
#pragma unroll
        for (int ni = 0; ni < 4; ++ni)
          acc[mi][ni] = MFMA_BF16(af[mi][ks], bfr[ni][ks], acc[mi][ni], 0, 0, 0);
  }

  // Q scale folds 1/sqrt(64) AND log2(e) so attention can use exp2 directly.
  const float qscale = (wsel == 0) ? 0.125f * 1.44269504f : 1.0f;
#pragma unroll
  for (int mi = 0; mi < 4; ++mi)
#pragma unroll
    for (int ni = 0; ni < 4; ++ni)
#pragma unroll
      for (int r = 0; r < 4; ++r) {
        int m = m0 + wr * 64 + mi * 16 + (lane >> 4) * 4 + r;
        int n = n0 + wc * 64 + ni * 16 + (lane & 15);
        float v = (acc[mi][ni][r] + bias[n]) * qscale;
        int b = m >> 11, t = m & 2047;
        int h = n >> 6, hd = n & 63;
        unsigned short bv16 = f2b(v);
        if (wsel == 2)
          Vto[(((size_t)b * 16 + h) * 64 + hd) * 2048 + t] = bv16;   // V^T [B,H,64,T]
        else if (wsel == 1)
          Ko[(((size_t)b * 16 + h) * 2048 + t) * 64 + hd] = bv16;    // [B,H,T,64]
        else
          Qo[(((size_t)b * 16 + h) * 2048 + t) * 64 + hd] = bv16;
      }
}

// ---------------- flash attention: 8 waves x 16 q-rows ----------------
// l computed via ones-MFMA; defer-max rescale (THR=8 in log2 domain);
// per-wave private P tile (no cross-wave barrier for P); XCD-chunked swizzle.
__global__ __launch_bounds__(512) void attn_kernel(
    const unsigned short* __restrict__ Qg, const unsigned short* __restrict__ Kg,
    const unsigned short* __restrict__ Vtg, unsigned short* __restrict__ Og) {
  __shared__ char smK[2][8192];
  __shared__ char smV[2][8192];
  __shared__ char smPT[8][2048];
  const int tid = threadIdx.x, lane = tid & 63, wvid = tid >> 6;
  const int g = lane >> 4, l15 = lane & 15;
  // XCD-chunked swizzle: 512 blocks, 64/XCD -> 4 consecutive heads per XCD
  const int lin = blockIdx.y * 16 + blockIdx.x;
  const int wg = (lin & 7) * 64 + (lin >> 3);
  const int bx = wg & 15, bh = wg >> 4;
  const int q0 = bx * 128 + wvid * 16;
  const unsigned short* Qh = Qg + (size_t)bh * 2048 * 64;
  const unsigned short* Kh = Kg + (size_t)bh * 2048 * 64;
  const unsigned short* Vh = Vtg + (size_t)bh * 64 * 2048;

  // Q frag (MFMA B operand: col q = l15, k rows = ks*32 + g*8 + j)
  bf16x8 qf[2];
#pragma unroll
  for (int ks = 0; ks < 2; ++ks)
    qf[ks] = *(const bf16x8*)(Qh + (size_t)(q0 + l15) * 64 + ks * 32 + g * 8);

  bf16x8 ones;
#pragma unroll
  for (int j = 0; j < 8; ++j) ones[j] = (short)0x3F80;  // bf16 1.0

  f32x4 acc[4];      // O^T frags [di]: row d = di*16+4g+r, col q = l15
  f32x4 accL;        // l via ones-MFMA (all elements equal per lane)
#pragma unroll
  for (int di = 0; di < 4; ++di) acc[di] = (f32x4){0.f, 0.f, 0.f, 0.f};
  accL = (f32x4){0.f, 0.f, 0.f, 0.f};
  float m = -1e30f;

#define STAGE(buf, kt)                                                         \
  {                                                                            \
    int c = wvid * 64 + lane;                                                  \
    int row = c >> 3;                                                          \
    int cb = (c & 7) ^ (row & 7);                                              \
    gload_lds16(Kh + (size_t)((kt) * 64 + row) * 64 + cb * 8,                  \
                smK[buf] + wvid * 1024);                                       \
    gload_lds16(Vh + (size_t)row * 2048 + (kt) * 64 + cb * 8,                  \
                smV[buf] + wvid * 1024);                                       \
  }

  STAGE(0, 0);
  __syncthreads();
  int buf = 0;
  char* P = smPT[wvid];

  for (int kt = 0; kt < 32; ++kt) {
    if (kt < 31) STAGE(buf ^ 1, kt + 1);

    // S^T = K * Q^T (64k x 16q per wave)
    f32x4 st[4];
#pragma unroll
    for (int ki = 0; ki < 4; ++ki) st[ki] = (f32x4){0.f, 0.f, 0.f, 0.f};
    __builtin_amdgcn_s_setprio(1);
#pragma unroll
    for (int ks = 0; ks < 2; ++ks)
#pragma unroll
      for (int ki = 0; ki < 4; ++ki) {
        int row = ki * 16 + l15;
        int addr = (row * 128 + ks * 64 + g * 16) ^ ((row & 7) << 4);
        bf16x8 kb = *(const bf16x8*)(smK[buf] + addr);
        st[ki] = MFMA_BF16(kb, qf[ks], st[ki], 0, 0, 0);
      }
    __builtin_amdgcn_s_setprio(0);

    // online softmax: lane owns q-row = l15; k-coverage via xor16+xor32
    float mx = -1e30f;
#pragma unroll
    for (int ki = 0; ki < 4; ++ki)
#pragma unroll
      for (int r = 0; r < 4; ++r) mx = fmaxf(mx, st[ki][r]);
    mx = fmaxf(mx, __shfl_xor(mx, 16, 64));
    mx = fmaxf(mx, __shfl_xor(mx, 32, 64));
    if (!__all(mx <= m + 8.f)) {   // defer-max: rescale only on big growth
      float mnew = fmaxf(m, mx);
      float alpha = fast_exp2(m - mnew);
#pragma unroll
      for (int di = 0; di < 4; ++di) acc[di] *= alpha;
      accL *= alpha;
      m = mnew;
    }
#pragma unroll
    for (int ki = 0; ki < 4; ++ki) {
#pragma unroll
      for (int r = 0; r < 4; ++r) st[ki][r] = fast_exp2(st[ki][r] - m);
      uint2 w;
      w.x = cvt_pk_bf16(st[ki][0], st[ki][1]);
      w.y = cvt_pk_bf16(st[ki][2], st[ki][3]);
      int addr = (l15 * 128 + ki * 32 + g * 8) ^ ((l15 & 7) << 4);
      *(uint2*)(P + addr) = w;
    }

    // O^T += V^T * P^T ; l += 1 * P^T (ones-MFMA)
#pragma unroll
    for (int ks = 0; ks < 2; ++ks) {
      int paddr = (l15 * 128 + ks * 64 + g * 16) ^ ((l15 & 7) << 4);
      bf16x8 pb = *(const bf16x8*)(P + paddr);
      __builtin_amdgcn_s_setprio(1);
      accL = MFMA_BF16(ones, pb, accL, 0, 0, 0);
#pragma unroll
      for (int di = 0; di < 4; ++di) {
        int d = di * 16 + l15;
        int vaddr = (d * 128 + ks * 64 + g * 16) ^ ((d & 7) << 4);
        bf16x8 vb = *(const bf16x8*)(smV[buf] + vaddr);
        acc[di] = MFMA_BF16(vb, pb, acc[di], 0, 0, 0);
      }
      __builtin_amdgcn_s_setprio(0);
    }

    __syncthreads();
    buf ^= 1;
  }

  // epilogue: normalize, transpose O^T -> O through per-wave P tile
  float inv = 1.0f / accL[0];
#pragma unroll
  for (int di = 0; di < 4; ++di) {
    uint2 w;
    w.x = cvt_pk_bf16(acc[di][0] * inv, acc[di][1] * inv);
    w.y = cvt_pk_bf16(acc[di][2] * inv, acc[di][3] * inv);
    int addr = (l15 * 128 + di * 32 + g * 8) ^ ((l15 & 7) << 4);
    *(uint2*)(P + addr) = w;
  }
  const int b = bh >> 4, h = bh & 15;
#pragma unroll
  for (int i = 0; i < 2; ++i) {
    int c = i * 64 + lane;
    int q = c >> 3, cb = c & 7;
    int addr = (q * 128 + cb * 16) ^ ((q & 7) << 4);
    uint4 v = *(const uint4*)(P + addr);
    int t = q0 + q;
    *(uint4*)(Og + ((size_t)(b * 2048 + t)) * 1024 + h * 64 + cb * 8) = v;
  }
}

// ---------------- output projection GEMM (fp32 out + bias) ----------------
__global__ __launch_bounds__(256) void out_gemm(
    const unsigned short* __restrict__ A, const unsigned short* __restrict__ W,
    const float* __restrict__ bias, float* __restrict__ out) {
  __shared__ char smA[16384];
  __shared__ char smB[16384];
  const int tid = threadIdx.x, lane = tid & 63, wvid = tid >> 6;
  const int wr = wvid >> 1, wc = wvid & 1;
  const int lin = blockIdx.y * 32 + blockIdx.x;
  const int wg = (lin & 7) * 32 + (lin >> 3);
  const int m0 = (wg & 31) * 128;
  const int n0 = (wg >> 5) * 128;

  f32x4 acc[4][4];
#pragma unroll
  for (int i = 0; i < 4; ++i)
#pragma unroll
    for (int j = 0; j < 4; ++j) acc[i][j] = (f32x4){0.f, 0.f, 0.f, 0.f};

  for (int kt = 0; kt < 16; ++kt) {
    const int k0 = kt * 64;
    __syncthreads();
#pragma unroll
    for (int i = 0; i < 4; ++i) {
      int c = (i * 4 + wvid) * 64 + lane;
      int row = c >> 3;
      int cb = (c & 7) ^ (row & 7);
      gload_lds16(A + (size_t)(m0 + row) * 1024 + k0 + cb * 8,
                  smA + (i * 4 + wvid) * 1024);
      gload_lds16(W + (size_t)(n0 + row) * 1024 + k0 + cb * 8,
                  smB + (i * 4 + wvid) * 1024);
    }
    __syncthreads();
    bf16x8 af[4][2], bfr[4][2];
#pragma unroll
    for (int mi = 0; mi < 4; ++mi)
#pragma unroll
      for (int ks = 0; ks < 2; ++ks) {
        int rowa = wr * 64 + mi * 16 + (lane & 15);
        int addra = (rowa * 128 + ks * 64 + ((lane >> 4) * 16)) ^ ((rowa & 7) << 4);
        af[mi][ks] = *(const bf16x8*)(smA + addra);
        int rowb = wc * 64 + mi * 16 + (lane & 15);
        int addrb = (rowb * 128 + ks * 64 + ((lane >> 4) * 16)) ^ ((rowb & 7) << 4);
        bfr[mi][ks] = *(const bf16x8*)(smB + addrb);
      }
#pragma unroll
    for (int ks = 0; ks < 2; ++ks)
#pragma unroll
      for (int mi = 0; mi < 4; ++mi)
#pragma unroll
        for (int ni = 0; ni < 4; ++ni)
          acc[mi][ni] = MFMA_BF16(af[mi][ks], bfr[ni][ks], acc[mi][ni], 0, 0, 0);
  }

#pragma unroll
  for (int mi = 0; mi < 4; ++mi)
#pragma unroll
    for (int ni = 0; ni < 4; ++ni)
#pragma unroll
      for (int r = 0; r < 4; ++r) {
        int mm = m0 + wr * 64 + mi * 16 + (lane >> 4) * 4 + r;
        int nn = n0 + wc * 64 + ni * 16 + (lane & 15);
        out[(size_t)mm * 1024 + nn] = acc[mi][ni][r] + bias[nn];
      }
}

extern "C" void kernel_launch(void* const* d_in, const int* in_sizes, int n_in,
                              void* d_out, int out_size, void* d_ws, size_t ws_size,
                              hipStream_t stream) {
  const float* x = (const float*)d_in[0];
  const float* Wq = (const float*)d_in[1];
  const float* bq = (const float*)d_in[2];
  const float* Wk = (const float*)d_in[3];
  const float* bk = (const float*)d_in[4];
  const float* Wv = (const float*)d_in[5];
  const float* bv = (const float*)d_in[6];
  const float* Wo = (const float*)d_in[7];
  const float* bo = (const float*)d_in[8];
  float* out = (float*)d_out;
  char* ws = (char*)d_ws;

  unsigned short* xb = (unsigned short*)(ws + 0);
  unsigned short* Ob = (unsigned short*)(ws + 0);  // reuse: attn writes after qkv reads
  unsigned short* wqb = (unsigned short*)(ws + 8388608);
  unsigned short* wkb = (unsigned short*)(ws + 10485760);
  unsigned short* wvb = (unsigned short*)(ws + 12582912);
  unsigned short* wob = (unsigned short*)(ws + 14680064);
  unsigned short* Qb = (unsigned short*)(ws + 16777216);
  unsigned short* Kb = (unsigned short*)(ws + 25165824);
  unsigned short* Vtb = (unsigned short*)(ws + 33554432);

  hipLaunchKernelGGL(cvt_all, dim3(8192), dim3(256), 0, stream,
                     x, Wq, Wk, Wv, Wo, xb, wqb, wkb, wvb, wob);
  hipLaunchKernelGGL(qkv_gemm, dim3(32, 24), dim3(256), 0, stream, xb, wqb, wkb, wvb,
                     bq, bk, bv, Qb, Kb, Vtb);
  hipLaunchKernelGGL(attn_kernel, dim3(16, 32), dim3(512), 0, stream, Qb, Kb, Vtb, Ob);
  hipLaunchKernelGGL(out_gemm, dim3(32, 8), dim3(256), 0, stream, Ob, wob, bo, out);
}

// Round 5
// 137.524 us; speedup vs baseline: 1.5296x; 1.0851x over previous
//
#include <hip/hip_runtime.h>
#include <cmath>

typedef __attribute__((ext_vector_type(8))) short bf16x8;
typedef __attribute__((ext_vector_type(4))) float f32x4;

#define MFMA_BF16 __builtin_amdgcn_mfma_f32_16x16x32_bf16

__device__ __forceinline__ unsigned short f2b(float f) {
  union { float f; unsigned u; } v; v.f = f;
  unsigned r = (v.u + 0x7FFFu + ((v.u >> 16) & 1u)) >> 16;
  return (unsigned short)r;
}

__device__ __forceinline__ unsigned cvt_pk_bf16(float lo, float hi) {
  unsigned r;
  asm("v_cvt_pk_bf16_f32 %0, %1, %2" : "=v"(r) : "v"(lo), "v"(hi));
  return r;
}

__device__ __forceinline__ float fast_exp2(float x) {
  float r;
  asm("v_exp_f32 %0, %1" : "=v"(r) : "v"(x));
  return r;
}

__device__ __forceinline__ void gload_lds16(const void* g, void* l) {
  __builtin_amdgcn_global_load_lds(
      (const __attribute__((address_space(1))) void*)g,
      (__attribute__((address_space(3))) void*)l, 16, 0, 0);
}

// ---------------- all fp32->bf16 conversions in ONE launch ----------------
__global__ __launch_bounds__(256) void cvt_all(
    const float* __restrict__ x, const float* __restrict__ Wq,
    const float* __restrict__ Wk, const float* __restrict__ Wv,
    const float* __restrict__ Wo,
    unsigned short* __restrict__ xb, unsigned short* __restrict__ wqb,
    unsigned short* __restrict__ wkb, unsigned short* __restrict__ wvb,
    unsigned short* __restrict__ wob) {
  int i = blockIdx.x * 256 + threadIdx.x;
  const float* src; unsigned short* dst; int off;
  if (i < 1048576)      { src = x;  dst = xb;  off = i; }
  else if (i < 1310720) { src = Wq; dst = wqb; off = i - 1048576; }
  else if (i < 1572864) { src = Wk; dst = wkb; off = i - 1310720; }
  else if (i < 1835008) { src = Wv; dst = wvb; off = i - 1572864; }
  else                  { src = Wo; dst = wob; off = i - 1835008; }
  float4 v = reinterpret_cast<const float4*>(src)[off];
  ushort4 o;
  o.x = f2b(v.x); o.y = f2b(v.y); o.z = f2b(v.z); o.w = f2b(v.w);
  reinterpret_cast<ushort4*>(dst)[off] = o;
}

// ---------------- fused QKV projection GEMM (2-phase dbuf) ----------------
__global__ __launch_bounds__(256) void qkv_gemm(
    const unsigned short* __restrict__ X,
    const unsigned short* __restrict__ Wq, const unsigned short* __restrict__ Wk,
    const unsigned short* __restrict__ Wv,
    const float* __restrict__ bq, const float* __restrict__ bk,
    const float* __restrict__ bv,
    unsigned short* __restrict__ Qo, unsigned short* __restrict__ Ko,
    unsigned short* __restrict__ Vto) {
  __shared__ char smA[2][16384];
  __shared__ char smB[2][16384];
  const int tid = threadIdx.x, lane = tid & 63, wvid = tid >> 6;
  const int wr = wvid >> 1, wc = wvid & 1;
  // 2-D XCD-chunked swizzle: XCD grid 4x2 over (m,bnall); per-XCD 8 m x 12 n
  const int lin = blockIdx.y * 32 + blockIdx.x;
  const int xcd = lin & 7, j = lin >> 3;           // j in [0,96)
  const int m_tile = (xcd >> 1) * 8 + (j & 7);     // [0,32)
  const int bnall = (xcd & 1) * 12 + (j >> 3);     // [0,24)
  const int m0 = m_tile * 128;
  const int wsel = bnall >> 3;          // 0=Q 1=K 2=V
  const int n0 = (bnall & 7) * 128;
  const unsigned short* W = (wsel == 0) ? Wq : (wsel == 1) ? Wk : Wv;
  const float* bias = (wsel == 0) ? bq : (wsel == 1) ? bk : bv;

  f32x4 acc[4][4];
#pragma unroll
  for (int i = 0; i < 4; ++i)
#pragma unroll
    for (int j2 = 0; j2 < 4; ++j2) acc[i][j2] = (f32x4){0.f, 0.f, 0.f, 0.f};

#define QSTAGE(b, kt)                                                          \
  {                                                                            \
    _Pragma("unroll") for (int i = 0; i < 4; ++i) {                            \
      int c = (i * 4 + wvid) * 64 + lane;                                      \
      int row = c >> 3;                                                        \
      int cb = (c & 7) ^ (row & 7);                                            \
      gload_lds16(X + (size_t)(m0 + row) * 1024 + (kt) * 64 + cb * 8,          \
                  smA[b] + (i * 4 + wvid) * 1024);                             \
      gload_lds16(W + (size_t)(n0 + row) * 1024 + (kt) * 64 + cb * 8,          \
                  smB[b] + (i * 4 + wvid) * 1024);                             \
    }                                                                          \
  }

  QSTAGE(0, 0);
  int buf = 0;
  for (int kt = 0; kt < 16; ++kt) {
    __syncthreads();                       // stage(kt) visible
    if (kt < 15) QSTAGE(buf ^ 1, kt + 1);  // prefetch next tile
    bf16x8 af[4][2], bfr[4][2];
#pragma unroll
    for (int mi = 0; mi < 4; ++mi)
#pragma unroll
      for (int ks = 0; ks < 2; ++ks) {
        int rowa = wr * 64 + mi * 16 + (lane & 15);
        int addra = (rowa * 128 + ks * 64 + ((lane >> 4) * 16)) ^ ((rowa & 7) << 4);
        af[mi][ks] = *(const bf16x8*)(smA[buf] + addra);
        int rowb = wc * 64 + mi * 16 + (lane & 15);
        int addrb = (rowb * 128 + ks * 64 + ((lane >> 4) * 16)) ^ ((rowb & 7) << 4);
        bfr[mi][ks] = *(const bf16x8*)(smB[buf] + addrb);
      }
    __builtin_amdgcn_s_setprio(1);
#pragma unroll
    for (int ks = 0; ks < 2; ++ks)
#pragma unroll
      for (int mi = 0; mi < 4; ++mi)
#pragma unroll
        for (int ni = 0; ni < 4; ++ni)
          acc[mi][ni] = MFMA_BF16(af[mi][ks], bfr[ni][ks], acc[mi][ni], 0, 0, 0);
    __builtin_amdgcn_s_setprio(0);
    buf ^= 1;
  }

  // Q scale folds 1/sqrt(64) AND log2(e) so attention can use exp2 directly.
  const float qscale = (wsel == 0) ? 0.125f * 1.44269504f : 1.0f;
#pragma unroll
  for (int mi = 0; mi < 4; ++mi)
#pragma unroll
    for (int ni = 0; ni < 4; ++ni)
#pragma unroll
      for (int r = 0; r < 4; ++r) {
        int m = m0 + wr * 64 + mi * 16 + (lane >> 4) * 4 + r;
        int n = n0 + wc * 64 + ni * 16 + (lane & 15);
        float v = (acc[mi][ni][r] + bias[n]) * qscale;
        int b = m >> 11, t = m & 2047;
        int h = n >> 6, hd = n & 63;
        unsigned short bv16 = f2b(v);
        if (wsel == 2)
          Vto[(((size_t)b * 16 + h) * 64 + hd) * 2048 + t] = bv16;   // V^T [B,H,64,T]
        else if (wsel == 1)
          Ko[(((size_t)b * 16 + h) * 2048 + t) * 64 + hd] = bv16;    // [B,H,T,64]
        else
          Qo[(((size_t)b * 16 + h) * 2048 + t) * 64 + hd] = bv16;
      }
}

// ---------------- flash attention: 8 waves x 16 q-rows ----------------
__global__ __launch_bounds__(512) void attn_kernel(
    const unsigned short* __restrict__ Qg, const unsigned short* __restrict__ Kg,
    const unsigned short* __restrict__ Vtg, unsigned short* __restrict__ Og) {
  __shared__ char smK[2][8192];
  __shared__ char smV[2][8192];
  __shared__ char smPT[8][2048];
  const int tid = threadIdx.x, lane = tid & 63, wvid = tid >> 6;
  const int g = lane >> 4, l15 = lane & 15;
  const int lin = blockIdx.y * 16 + blockIdx.x;
  const int wg = (lin & 7) * 64 + (lin >> 3);
  const int bx = wg & 15, bh = wg >> 4;
  const int q0 = bx * 128 + wvid * 16;
  const unsigned short* Qh = Qg + (size_t)bh * 2048 * 64;
  const unsigned short* Kh = Kg + (size_t)bh * 2048 * 64;
  const unsigned short* Vh = Vtg + (size_t)bh * 64 * 2048;

  bf16x8 qf[2];
#pragma unroll
  for (int ks = 0; ks < 2; ++ks)
    qf[ks] = *(const bf16x8*)(Qh + (size_t)(q0 + l15) * 64 + ks * 32 + g * 8);

  bf16x8 ones;
#pragma unroll
  for (int j = 0; j < 8; ++j) ones[j] = (short)0x3F80;  // bf16 1.0

  f32x4 acc[4];
  f32x4 accL;
#pragma unroll
  for (int di = 0; di < 4; ++di) acc[di] = (f32x4){0.f, 0.f, 0.f, 0.f};
  accL = (f32x4){0.f, 0.f, 0.f, 0.f};
  float m = -1e30f;

#define STAGE(buf, kt)                                                         \
  {                                                                            \
    int c = wvid * 64 + lane;                                                  \
    int row = c >> 3;                                                          \
    int cb = (c & 7) ^ (row & 7);                                              \
    gload_lds16(Kh + (size_t)((kt) * 64 + row) * 64 + cb * 8,                  \
                smK[buf] + wvid * 1024);                                       \
    gload_lds16(Vh + (size_t)row * 2048 + (kt) * 64 + cb * 8,                  \
                smV[buf] + wvid * 1024);                                       \
  }

  STAGE(0, 0);
  __syncthreads();
  int buf = 0;
  char* P = smPT[wvid];

  for (int kt = 0; kt < 32; ++kt) {
    if (kt < 31) STAGE(buf ^ 1, kt + 1);

    f32x4 st[4];
#pragma unroll
    for (int ki = 0; ki < 4; ++ki) st[ki] = (f32x4){0.f, 0.f, 0.f, 0.f};
    __builtin_amdgcn_s_setprio(1);
#pragma unroll
    for (int ks = 0; ks < 2; ++ks)
#pragma unroll
      for (int ki = 0; ki < 4; ++ki) {
        int row = ki * 16 + l15;
        int addr = (row * 128 + ks * 64 + g * 16) ^ ((row & 7) << 4);
        bf16x8 kb = *(const bf16x8*)(smK[buf] + addr);
        st[ki] = MFMA_BF16(kb, qf[ks], st[ki], 0, 0, 0);
      }
    __builtin_amdgcn_s_setprio(0);

    float mx = -1e30f;
#pragma unroll
    for (int ki = 0; ki < 4; ++ki)
#pragma unroll
      for (int r = 0; r < 4; ++r) mx = fmaxf(mx, st[ki][r]);
    mx = fmaxf(mx, __shfl_xor(mx, 16, 64));
    mx = fmaxf(mx, __shfl_xor(mx, 32, 64));
    if (!__all(mx <= m + 8.f)) {
      float mnew = fmaxf(m, mx);
      float alpha = fast_exp2(m - mnew);
#pragma unroll
      for (int di = 0; di < 4; ++di) acc[di] *= alpha;
      accL *= alpha;
      m = mnew;
    }
#pragma unroll
    for (int ki = 0; ki < 4; ++ki) {
#pragma unroll
      for (int r = 0; r < 4; ++r) st[ki][r] = fast_exp2(st[ki][r] - m);
      uint2 w;
      w.x = cvt_pk_bf16(st[ki][0], st[ki][1]);
      w.y = cvt_pk_bf16(st[ki][2], st[ki][3]);
      int addr = (l15 * 128 + ki * 32 + g * 8) ^ ((l15 & 7) << 4);
      *(uint2*)(P + addr) = w;
    }

#pragma unroll
    for (int ks = 0; ks < 2; ++ks) {
      int paddr = (l15 * 128 + ks * 64 + g * 16) ^ ((l15 & 7) << 4);
      bf16x8 pb = *(const bf16x8*)(P + paddr);
      __builtin_amdgcn_s_setprio(1);
      accL = MFMA_BF16(ones, pb, accL, 0, 0, 0);
#pragma unroll
      for (int di = 0; di < 4; ++di) {
        int d = di * 16 + l15;
        int vaddr = (d * 128 + ks * 64 + g * 16) ^ ((d & 7) << 4);
        bf16x8 vb = *(const bf16x8*)(smV[buf] + vaddr);
        acc[di] = MFMA_BF16(vb, pb, acc[di], 0, 0, 0);
      }
      __builtin_amdgcn_s_setprio(0);
    }

    __syncthreads();
    buf ^= 1;
  }

  float inv = 1.0f / accL[0];
#pragma unroll
  for (int di = 0; di < 4; ++di) {
    uint2 w;
    w.x = cvt_pk_bf16(acc[di][0] * inv, acc[di][1] * inv);
    w.y = cvt_pk_bf16(acc[di][2] * inv, acc[di][3] * inv);
    int addr = (l15 * 128 + di * 32 + g * 8) ^ ((l15 & 7) << 4);
    *(uint2*)(P + addr) = w;
  }
  const int b = bh >> 4, h = bh & 15;
#pragma unroll
  for (int i = 0; i < 2; ++i) {
    int c = i * 64 + lane;
    int q = c >> 3, cb = c & 7;
    int addr = (q * 128 + cb * 16) ^ ((q & 7) << 4);
    uint4 v = *(const uint4*)(P + addr);
    int t = q0 + q;
    *(uint4*)(Og + ((size_t)(b * 2048 + t)) * 1024 + h * 64 + cb * 8) = v;
  }
}

// ---------------- output projection GEMM (2-phase dbuf, fp32 out) ----------------
__global__ __launch_bounds__(256) void out_gemm(
    const unsigned short* __restrict__ A, const unsigned short* __restrict__ W,
    const float* __restrict__ bias, float* __restrict__ out) {
  __shared__ char smA[2][16384];
  __shared__ char smB[2][16384];
  const int tid = threadIdx.x, lane = tid & 63, wvid = tid >> 6;
  const int wr = wvid >> 1, wc = wvid & 1;
  // 2-D XCD chunk: XCD owns 4 m-tiles x 8 n-tiles
  const int lin = blockIdx.y * 32 + blockIdx.x;
  const int xcd = lin & 7, j = lin >> 3;      // j in [0,32)
  const int m0 = (xcd * 4 + (j & 3)) * 128;
  const int n0 = (j >> 2) * 128;

  f32x4 acc[4][4];
#pragma unroll
  for (int i = 0; i < 4; ++i)
#pragma unroll
    for (int j2 = 0; j2 < 4; ++j2) acc[i][j2] = (f32x4){0.f, 0.f, 0.f, 0.f};

#define OSTAGE(b, kt)                                                          \
  {                                                                            \
    _Pragma("unroll") for (int i = 0; i < 4; ++i) {                            \
      int c = (i * 4 + wvid) * 64 + lane;                                      \
      int row = c >> 3;                                                        \
      int cb = (c & 7) ^ (row & 7);                                            \
      gload_lds16(A + (size_t)(m0 + row) * 1024 + (kt) * 64 + cb * 8,          \
                  smA[b] + (i * 4 + wvid) * 1024);                             \
      gload_lds16(W + (size_t)(n0 + row) * 1024 + (kt) * 64 + cb * 8,          \
                  smB[b] + (i * 4 + wvid) * 1024);                             \
    }                                                                          \
  }

  OSTAGE(0, 0);
  int buf = 0;
  for (int kt = 0; kt < 16; ++kt) {
    __syncthreads();
    if (kt < 15) OSTAGE(buf ^ 1, kt + 1);
    bf16x8 af[4][2], bfr[4][2];
#pragma unroll
    for (int mi = 0; mi < 4; ++mi)
#pragma unroll
      for (int ks = 0; ks < 2; ++ks) {
        int rowa = wr * 64 + mi * 16 + (lane & 15);
        int addra = (rowa * 128 + ks * 64 + ((lane >> 4) * 16)) ^ ((rowa & 7) << 4);
        af[mi][ks] = *(const bf16x8*)(smA[buf] + addra);
        int rowb = wc * 64 + mi * 16 + (lane & 15);
        int addrb = (rowb * 128 + ks * 64 + ((lane >> 4) * 16)) ^ ((rowb & 7) << 4);
        bfr[mi][ks] = *(const bf16x8*)(smB[buf] + addrb);
      }
    __builtin_amdgcn_s_setprio(1);
#pragma unroll
    for (int ks = 0; ks < 2; ++ks)
#pragma unroll
      for (int mi = 0; mi < 4; ++mi)
#pragma unroll
        for (int ni = 0; ni < 4; ++ni)
          acc[mi][ni] = MFMA_BF16(af[mi][ks], bfr[ni][ks], acc[mi][ni], 0, 0, 0);
    __builtin_amdgcn_s_setprio(0);
    buf ^= 1;
  }

#pragma unroll
  for (int mi = 0; mi < 4; ++mi)
#pragma unroll
    for (int ni = 0; ni < 4; ++ni)
#pragma unroll
      for (int r = 0; r < 4; ++r) {
        int mm = m0 + wr * 64 + mi * 16 + (lane >> 4) * 4 + r;
        int nn = n0 + wc * 64 + ni * 16 + (lane & 15);
        out[(size_t)mm * 1024 + nn] = acc[mi][ni][r] + bias[nn];
      }
}

extern "C" void kernel_launch(void* const* d_in, const int* in_sizes, int n_in,
                              void* d_out, int out_size, void* d_ws, size_t ws_size,
                              hipStream_t stream) {
  const float* x = (const float*)d_in[0];
  const float* Wq = (const float*)d_in[1];
  const float* bq = (const float*)d_in[2];
  const float* Wk = (const float*)d_in[3];
  const float* bk = (const float*)d_in[4];
  const float* Wv = (const float*)d_in[5];
  const float* bv = (const float*)d_in[6];
  const float* Wo = (const float*)d_in[7];
  const float* bo = (const float*)d_in[8];
  float* out = (float*)d_out;
  char* ws = (char*)d_ws;

  unsigned short* xb = (unsigned short*)(ws + 0);
  unsigned short* Ob = (unsigned short*)(ws + 0);  // reuse: attn writes after qkv reads
  unsigned short* wqb = (unsigned short*)(ws + 8388608);
  unsigned short* wkb = (unsigned short*)(ws + 10485760);
  unsigned short* wvb = (unsigned short*)(ws + 12582912);
  unsigned short* wob = (unsigned short*)(ws + 14680064);
  unsigned short* Qb = (unsigned short*)(ws + 16777216);
  unsigned short* Kb = (unsigned short*)(ws + 25165824);
  unsigned short* Vtb = (unsigned short*)(ws + 33554432);

  hipLaunchKernelGGL(cvt_all, dim3(8192), dim3(256), 0, stream,
                     x, Wq, Wk, Wv, Wo, xb, wqb, wkb, wvb, wob);
  hipLaunchKernelGGL(qkv_gemm, dim3(32, 24), dim3(256), 0, stream, xb, wqb, wkb, wvb,
                     bq, bk, bv, Qb, Kb, Vtb);
  hipLaunchKernelGGL(attn_kernel, dim3(16, 32), dim3(512), 0, stream, Qb, Kb, Vtb, Ob);
  hipLaunchKernelGGL(out_gemm, dim3(32, 8), dim3(256), 0, stream, Ob, wob, bo, out);
}

// Round 6
// 123.196 us; speedup vs baseline: 1.7075x; 1.1163x over previous
//
#include <hip/hip_runtime.h>
#include <cmath>

typedef __attribute__((ext_vector_type(8))) short bf16x8;
typedef __attribute__((ext_vector_type(4))) float f32x4;

#define MFMA_BF16 __builtin_amdgcn_mfma_f32_16x16x32_bf16

__device__ __forceinline__ unsigned short f2b(float f) {
  union { float f; unsigned u; } v; v.f = f;
  unsigned r = (v.u + 0x7FFFu + ((v.u >> 16) & 1u)) >> 16;
  return (unsigned short)r;
}

__device__ __forceinline__ unsigned cvt_pk_bf16(float lo, float hi) {
  unsigned r;
  asm("v_cvt_pk_bf16_f32 %0, %1, %2" : "=v"(r) : "v"(lo), "v"(hi));
  return r;
}

__device__ __forceinline__ float fast_exp2(float x) {
  float r;
  asm("v_exp_f32 %0, %1" : "=v"(r) : "v"(x));
  return r;
}

__device__ __forceinline__ void gload_lds16(const void* g, void* l) {
  __builtin_amdgcn_global_load_lds(
      (const __attribute__((address_space(1))) void*)g,
      (__attribute__((address_space(3))) void*)l, 16, 0, 0);
}

// ---------------- all fp32->bf16 conversions in ONE launch ----------------
__global__ __launch_bounds__(256) void cvt_all(
    const float* __restrict__ x, const float* __restrict__ Wq,
    const float* __restrict__ Wk, const float* __restrict__ Wv,
    const float* __restrict__ Wo,
    unsigned short* __restrict__ xb, unsigned short* __restrict__ wqb,
    unsigned short* __restrict__ wkb, unsigned short* __restrict__ wvb,
    unsigned short* __restrict__ wob) {
  int i = blockIdx.x * 256 + threadIdx.x;
  const float* src; unsigned short* dst; int off;
  if (i < 1048576)      { src = x;  dst = xb;  off = i; }
  else if (i < 1310720) { src = Wq; dst = wqb; off = i - 1048576; }
  else if (i < 1572864) { src = Wk; dst = wkb; off = i - 1310720; }
  else if (i < 1835008) { src = Wv; dst = wvb; off = i - 1572864; }
  else                  { src = Wo; dst = wob; off = i - 1835008; }
  float4 v = reinterpret_cast<const float4*>(src)[off];
  ushort4 o;
  o.x = f2b(v.x); o.y = f2b(v.y); o.z = f2b(v.z); o.w = f2b(v.w);
  reinterpret_cast<ushort4*>(dst)[off] = o;
}

// ---------------- fused QKV projection GEMM (8 waves, 2-phase dbuf) ----------------
// 128x128 tile, 512 threads: 8 waves each own 32x64 (wr in [0,4), wc in [0,2)).
// 4 waves/SIMD at 2 blocks/CU for latency hiding.
__global__ __launch_bounds__(512, 4) void qkv_gemm(
    const unsigned short* __restrict__ X,
    const unsigned short* __restrict__ Wq, const unsigned short* __restrict__ Wk,
    const unsigned short* __restrict__ Wv,
    const float* __restrict__ bq, const float* __restrict__ bk,
    const float* __restrict__ bv,
    unsigned short* __restrict__ Qo, unsigned short* __restrict__ Ko,
    unsigned short* __restrict__ Vto) {
  __shared__ char smA[2][16384];
  __shared__ char smB[2][16384];
  const int tid = threadIdx.x, lane = tid & 63, wvid = tid >> 6;
  const int g = lane >> 4, l15 = lane & 15;
  const int wr = wvid >> 1, wc = wvid & 1;
  // 2-D XCD-chunked swizzle: XCD grid 4x2 over (m,bnall); per-XCD 8 m x 12 n
  const int lin = blockIdx.y * 32 + blockIdx.x;
  const int xcd = lin & 7, j = lin >> 3;           // j in [0,96)
  const int m_tile = (xcd >> 1) * 8 + (j & 7);     // [0,32)
  const int bnall = (xcd & 1) * 12 + (j >> 3);     // [0,24)
  const int m0 = m_tile * 128;
  const int wsel = bnall >> 3;          // 0=Q 1=K 2=V
  const int n0 = (bnall & 7) * 128;
  const unsigned short* W = (wsel == 0) ? Wq : (wsel == 1) ? Wk : Wv;
  const float* bias = (wsel == 0) ? bq : (wsel == 1) ? bk : bv;

  f32x4 acc[2][4];
#pragma unroll
  for (int i = 0; i < 2; ++i)
#pragma unroll
    for (int j2 = 0; j2 < 4; ++j2) acc[i][j2] = (f32x4){0.f, 0.f, 0.f, 0.f};

#define QSTAGE(b, kt)                                                          \
  {                                                                            \
    _Pragma("unroll") for (int i = 0; i < 2; ++i) {                            \
      int c = (i * 8 + wvid) * 64 + lane;                                      \
      int row = c >> 3;                                                        \
      int cb = (c & 7) ^ (row & 7);                                            \
      gload_lds16(X + (size_t)(m0 + row) * 1024 + (kt) * 64 + cb * 8,          \
                  smA[b] + (i * 8 + wvid) * 1024);                             \
      gload_lds16(W + (size_t)(n0 + row) * 1024 + (kt) * 64 + cb * 8,          \
                  smB[b] + (i * 8 + wvid) * 1024);                             \
    }                                                                          \
  }

  QSTAGE(0, 0);
  int buf = 0;
  for (int kt = 0; kt < 16; ++kt) {
    __syncthreads();                       // stage(kt) visible
    if (kt < 15) QSTAGE(buf ^ 1, kt + 1);  // prefetch next tile
    bf16x8 af[2][2], bfr[4][2];
#pragma unroll
    for (int mi = 0; mi < 2; ++mi)
#pragma unroll
      for (int ks = 0; ks < 2; ++ks) {
        int rowa = wr * 32 + mi * 16 + l15;
        int addra = (rowa * 128 + ks * 64 + g * 16) ^ ((rowa & 7) << 4);
        af[mi][ks] = *(const bf16x8*)(smA[buf] + addra);
      }
#pragma unroll
    for (int ni = 0; ni < 4; ++ni)
#pragma unroll
      for (int ks = 0; ks < 2; ++ks) {
        int rowb = wc * 64 + ni * 16 + l15;
        int addrb = (rowb * 128 + ks * 64 + g * 16) ^ ((rowb & 7) << 4);
        bfr[ni][ks] = *(const bf16x8*)(smB[buf] + addrb);
      }
    __builtin_amdgcn_s_setprio(1);
#pragma unroll
    for (int ks = 0; ks < 2; ++ks)
#pragma unroll
      for (int mi = 0; mi < 2; ++mi)
#pragma unroll
        for (int ni = 0; ni < 4; ++ni)
          acc[mi][ni] = MFMA_BF16(af[mi][ks], bfr[ni][ks], acc[mi][ni], 0, 0, 0);
    __builtin_amdgcn_s_setprio(0);
    buf ^= 1;
  }

  // Q scale folds 1/sqrt(64) AND log2(e) so attention can use exp2 directly.
  const float qscale = (wsel == 0) ? 0.125f * 1.44269504f : 1.0f;
#pragma unroll
  for (int mi = 0; mi < 2; ++mi)
#pragma unroll
    for (int ni = 0; ni < 4; ++ni)
#pragma unroll
      for (int r = 0; r < 4; ++r) {
        int m = m0 + wr * 32 + mi * 16 + g * 4 + r;
        int n = n0 + wc * 64 + ni * 16 + l15;
        float v = (acc[mi][ni][r] + bias[n]) * qscale;
        int b = m >> 11, t = m & 2047;
        int h = n >> 6, hd = n & 63;
        unsigned short bv16 = f2b(v);
        if (wsel == 2)
          Vto[(((size_t)b * 16 + h) * 64 + hd) * 2048 + t] = bv16;   // V^T [B,H,64,T]
        else if (wsel == 1)
          Ko[(((size_t)b * 16 + h) * 2048 + t) * 64 + hd] = bv16;    // [B,H,T,64]
        else
          Qo[(((size_t)b * 16 + h) * 2048 + t) * 64 + hd] = bv16;
      }
}

// ---------------- flash attention: 8 waves x 16 q-rows ----------------
__global__ __launch_bounds__(512) void attn_kernel(
    const unsigned short* __restrict__ Qg, const unsigned short* __restrict__ Kg,
    const unsigned short* __restrict__ Vtg, unsigned short* __restrict__ Og) {
  __shared__ char smK[2][8192];
  __shared__ char smV[2][8192];
  __shared__ char smPT[8][2048];
  const int tid = threadIdx.x, lane = tid & 63, wvid = tid >> 6;
  const int g = lane >> 4, l15 = lane & 15;
  const int lin = blockIdx.y * 16 + blockIdx.x;
  const int wg = (lin & 7) * 64 + (lin >> 3);
  const int bx = wg & 15, bh = wg >> 4;
  const int q0 = bx * 128 + wvid * 16;
  const unsigned short* Qh = Qg + (size_t)bh * 2048 * 64;
  const unsigned short* Kh = Kg + (size_t)bh * 2048 * 64;
  const unsigned short* Vh = Vtg + (size_t)bh * 64 * 2048;

  bf16x8 qf[2];
#pragma unroll
  for (int ks = 0; ks < 2; ++ks)
    qf[ks] = *(const bf16x8*)(Qh + (size_t)(q0 + l15) * 64 + ks * 32 + g * 8);

  bf16x8 ones;
#pragma unroll
  for (int j = 0; j < 8; ++j) ones[j] = (short)0x3F80;  // bf16 1.0

  f32x4 acc[4];
  f32x4 accL;
#pragma unroll
  for (int di = 0; di < 4; ++di) acc[di] = (f32x4){0.f, 0.f, 0.f, 0.f};
  accL = (f32x4){0.f, 0.f, 0.f, 0.f};
  float m = -1e30f;

#define STAGE(buf, kt)                                                         \
  {                                                                            \
    int c = wvid * 64 + lane;                                                  \
    int row = c >> 3;                                                          \
    int cb = (c & 7) ^ (row & 7);                                              \
    gload_lds16(Kh + (size_t)((kt) * 64 + row) * 64 + cb * 8,                  \
                smK[buf] + wvid * 1024);                                       \
    gload_lds16(Vh + (size_t)row * 2048 + (kt) * 64 + cb * 8,                  \
                smV[buf] + wvid * 1024);                                       \
  }

  STAGE(0, 0);
  __syncthreads();
  int buf = 0;
  char* P = smPT[wvid];

  for (int kt = 0; kt < 32; ++kt) {
    if (kt < 31) STAGE(buf ^ 1, kt + 1);

    f32x4 st[4];
#pragma unroll
    for (int ki = 0; ki < 4; ++ki) st[ki] = (f32x4){0.f, 0.f, 0.f, 0.f};
    __builtin_amdgcn_s_setprio(1);
#pragma unroll
    for (int ks = 0; ks < 2; ++ks)
#pragma unroll
      for (int ki = 0; ki < 4; ++ki) {
        int row = ki * 16 + l15;
        int addr = (row * 128 + ks * 64 + g * 16) ^ ((row & 7) << 4);
        bf16x8 kb = *(const bf16x8*)(smK[buf] + addr);
        st[ki] = MFMA_BF16(kb, qf[ks], st[ki], 0, 0, 0);
      }
    __builtin_amdgcn_s_setprio(0);

    float mx = -1e30f;
#pragma unroll
    for (int ki = 0; ki < 4; ++ki)
#pragma unroll
      for (int r = 0; r < 4; ++r) mx = fmaxf(mx, st[ki][r]);
    mx = fmaxf(mx, __shfl_xor(mx, 16, 64));
    mx = fmaxf(mx, __shfl_xor(mx, 32, 64));
    if (!__all(mx <= m + 8.f)) {
      float mnew = fmaxf(m, mx);
      float alpha = fast_exp2(m - mnew);
#pragma unroll
      for (int di = 0; di < 4; ++di) acc[di] *= alpha;
      accL *= alpha;
      m = mnew;
    }
#pragma unroll
    for (int ki = 0; ki < 4; ++ki) {
#pragma unroll
      for (int r = 0; r < 4; ++r) st[ki][r] = fast_exp2(st[ki][r] - m);
      uint2 w;
      w.x = cvt_pk_bf16(st[ki][0], st[ki][1]);
      w.y = cvt_pk_bf16(st[ki][2], st[ki][3]);
      int addr = (l15 * 128 + ki * 32 + g * 8) ^ ((l15 & 7) << 4);
      *(uint2*)(P + addr) = w;
    }

#pragma unroll
    for (int ks = 0; ks < 2; ++ks) {
      int paddr = (l15 * 128 + ks * 64 + g * 16) ^ ((l15 & 7) << 4);
      bf16x8 pb = *(const bf16x8*)(P + paddr);
      __builtin_amdgcn_s_setprio(1);
      accL = MFMA_BF16(ones, pb, accL, 0, 0, 0);
#pragma unroll
      for (int di = 0; di < 4; ++di) {
        int d = di * 16 + l15;
        int vaddr = (d * 128 + ks * 64 + g * 16) ^ ((d & 7) << 4);
        bf16x8 vb = *(const bf16x8*)(smV[buf] + vaddr);
        acc[di] = MFMA_BF16(vb, pb, acc[di], 0, 0, 0);
      }
      __builtin_amdgcn_s_setprio(0);
    }

    __syncthreads();
    buf ^= 1;
  }

  float inv = 1.0f / accL[0];
#pragma unroll
  for (int di = 0; di < 4; ++di) {
    uint2 w;
    w.x = cvt_pk_bf16(acc[di][0] * inv, acc[di][1] * inv);
    w.y = cvt_pk_bf16(acc[di][2] * inv, acc[di][3] * inv);
    int addr = (l15 * 128 + di * 32 + g * 8) ^ ((l15 & 7) << 4);
    *(uint2*)(P + addr) = w;
  }
  const int b = bh >> 4, h = bh & 15;
#pragma unroll
  for (int i = 0; i < 2; ++i) {
    int c = i * 64 + lane;
    int q = c >> 3, cb = c & 7;
    int addr = (q * 128 + cb * 16) ^ ((q & 7) << 4);
    uint4 v = *(const uint4*)(P + addr);
    int t = q0 + q;
    *(uint4*)(Og + ((size_t)(b * 2048 + t)) * 1024 + h * 64 + cb * 8) = v;
  }
}

// ---------------- output projection GEMM (8 waves, 2-phase dbuf, fp32 out) -------
__global__ __launch_bounds__(512, 4) void out_gemm(
    const unsigned short* __restrict__ A, const unsigned short* __restrict__ W,
    const float* __restrict__ bias, float* __restrict__ out) {
  __shared__ char smA[2][16384];
  __shared__ char smB[2][16384];
  const int tid = threadIdx.x, lane = tid & 63, wvid = tid >> 6;
  const int g = lane >> 4, l15 = lane & 15;
  const int wr = wvid >> 1, wc = wvid & 1;
  // 2-D XCD chunk: XCD owns 4 m-tiles x 8 n-tiles
  const int lin = blockIdx.y * 32 + blockIdx.x;
  const int xcd = lin & 7, j = lin >> 3;      // j in [0,32)
  const int m0 = (xcd * 4 + (j & 3)) * 128;
  const int n0 = (j >> 2) * 128;

  f32x4 acc[2][4];
#pragma unroll
  for (int i = 0; i < 2; ++i)
#pragma unroll
    for (int j2 = 0; j2 < 4; ++j2) acc[i][j2] = (f32x4){0.f, 0.f, 0.f, 0.f};

#define OSTAGE(b, kt)                                                          \
  {                                                                            \
    _Pragma("unroll") for (int i = 0; i < 2; ++i) {                            \
      int c = (i * 8 + wvid) * 64 + lane;                                      \
      int row = c >> 3;                                                        \
      int cb = (c & 7) ^ (row & 7);                                            \
      gload_lds16(A + (size_t)(m0 + row) * 1024 + (kt) * 64 + cb * 8,          \
                  smA[b] + (i * 8 + wvid) * 1024);                             \
      gload_lds16(W + (size_t)(n0 + row) * 1024 + (kt) * 64 + cb * 8,          \
                  smB[b] + (i * 8 + wvid) * 1024);                             \
    }                                                                          \
  }

  OSTAGE(0, 0);
  int buf = 0;
  for (int kt = 0; kt < 16; ++kt) {
    __syncthreads();
    if (kt < 15) OSTAGE(buf ^ 1, kt + 1);
    bf16x8 af[2][2], bfr[4][2];
#pragma unroll
    for (int mi = 0; mi < 2; ++mi)
#pragma unroll
      for (int ks = 0; ks < 2; ++ks) {
        int rowa = wr * 32 + mi * 16 + l15;
        int addra = (rowa * 128 + ks * 64 + g * 16) ^ ((rowa & 7) << 4);
        af[mi][ks] = *(const bf16x8*)(smA[buf] + addra);
      }
#pragma unroll
    for (int ni = 0; ni < 4; ++ni)
#pragma unroll
      for (int ks = 0; ks < 2; ++ks) {
        int rowb = wc * 64 + ni * 16 + l15;
        int addrb = (rowb * 128 + ks * 64 + g * 16) ^ ((rowb & 7) << 4);
        bfr[ni][ks] = *(const bf16x8*)(smB[buf] + addrb);
      }
    __builtin_amdgcn_s_setprio(1);
#pragma unroll
    for (int ks = 0; ks < 2; ++ks)
#pragma unroll
      for (int mi = 0; mi < 2; ++mi)
#pragma unroll
        for (int ni = 0; ni < 4; ++ni)
          acc[mi][ni] = MFMA_BF16(af[mi][ks], bfr[ni][ks], acc[mi][ni], 0, 0, 0);
    __builtin_amdgcn_s_setprio(0);
    buf ^= 1;
  }

#pragma unroll
  for (int mi = 0; mi < 2; ++mi)
#pragma unroll
    for (int ni = 0; ni < 4; ++ni)
#pragma unroll
      for (int r = 0; r < 4; ++r) {
        int mm = m0 + wr * 32 + mi * 16 + g * 4 + r;
        int nn = n0 + wc * 64 + ni * 16 + l15;
        out[(size_t)mm * 1024 + nn] = acc[mi][ni][r] + bias[nn];
      }
}

extern "C" void kernel_launch(void* const* d_in, const int* in_sizes, int n_in,
                              void* d_out, int out_size, void* d_ws, size_t ws_size,
                              hipStream_t stream) {
  const float* x = (const float*)d_in[0];
  const float* Wq = (const float*)d_in[1];
  const float* bq = (const float*)d_in[2];
  const float* Wk = (const float*)d_in[3];
  const float* bk = (const float*)d_in[4];
  const float* Wv = (const float*)d_in[5];
  const float* bv = (const float*)d_in[6];
  const float* Wo = (const float*)d_in[7];
  const float* bo = (const float*)d_in[8];
  float* out = (float*)d_out;
  char* ws = (char*)d_ws;

  unsigned short* xb = (unsigned short*)(ws + 0);
  unsigned short* Ob = (unsigned short*)(ws + 0);  // reuse: attn writes after qkv reads
  unsigned short* wqb = (unsigned short*)(ws + 8388608);
  unsigned short* wkb = (unsigned short*)(ws + 10485760);
  unsigned short* wvb = (unsigned short*)(ws + 12582912);
  unsigned short* wob = (unsigned short*)(ws + 14680064);
  unsigned short* Qb = (unsigned short*)(ws + 16777216);
  unsigned short* Kb = (unsigned short*)(ws + 25165824);
  unsigned short* Vtb = (unsigned short*)(ws + 33554432);

  hipLaunchKernelGGL(cvt_all, dim3(8192), dim3(256), 0, stream,
                     x, Wq, Wk, Wv, Wo, xb, wqb, wkb, wvb, wob);
  hipLaunchKernelGGL(qkv_gemm, dim3(32, 24), dim3(512), 0, stream, xb, wqb, wkb, wvb,
                     bq, bk, bv, Qb, Kb, Vtb);
  hipLaunchKernelGGL(attn_kernel, dim3(16, 32), dim3(512), 0, stream, Qb, Kb, Vtb, Ob);
  hipLaunchKernelGGL(out_gemm, dim3(32, 8), dim3(512), 0, stream, Ob, wob, bo, out);
}